// Round 16
// baseline (3804.439 us; speedup 1.0000x reference)
//
#include <hip/hip_runtime.h>
#include <hip/hip_cooperative_groups.h>
#include <math.h>

#define TT 400
#define BBATCH 256
#define VDIM 128
#define CDIM 64
#define HDIM 512
#define NCHUNK 11    // 11 chunks x 64 k (2 k-halves of 32)
#define TSPLIT 160   // t >= TSPLIT handled by the single cooperative tail kernel
#define NTHRESH 8    // L <= NTHRESH: narrow GEMV phase-1 path

namespace cg = cooperative_groups;

typedef double d4 __attribute__((ext_vector_type(4)));

__device__ __forceinline__ double sigd(double x) {
  if (x >= 0.0) { double e = exp(-x); return 1.0 / (1.0 + e); }
  double e = exp(x); return e / (1.0 + e);
}

__global__ __launch_bounds__(256) void k_init(
    float* __restrict__ wtro, const float* __restrict__ W_out,
    float* __restrict__ wtrc, const float* __restrict__ W_ctrl,
    int* __restrict__ rowlive, int* __restrict__ alive, int* __restrict__ nlive)
{
  const int i = blockIdx.x * 256 + threadIdx.x;
  if (i < HDIM * CDIM) {
    const int k = i >> 6, c = i & 63;
    wtro[i] = W_out[c * HDIM + k];
  }
  if (i < 577 * CDIM) {
    const int k = i >> 6, c = i & 63;
    wtrc[i] = W_ctrl[c * 577 + k];
  }
  if (i < BBATCH) rowlive[i] = 1;
  if (i < TT) { alive[i] = 0; nlive[i] = 0; }
}

// ---------------- phase bodies ----------------

__device__ __forceinline__ void phase1_body(
    const float* __restrict__ X, const float* __restrict__ W_ih,
    const float* __restrict__ W_hh, const float* __restrict__ b_ih,
    const float* __restrict__ b_hh, const double* __restrict__ hR,
    double* __restrict__ hW, double* __restrict__ cst,
    const double* __restrict__ ybar, int t, int cb, int rb, int tid,
    double (*aF)[2][8][66], float (*bF)[2][2][8][68])
{
  const int lane = tid & 63;
  const int wid  = tid >> 6;
  const int r0   = rb * 16;
  const int hbase = cb * 8;

  double* gsp = &aF[0][0][0][0];   // gate staging aliases aF after the k-loop

  const int sA  = tid & 7;          // k-slot
  const int khA = (tid >> 3) & 1;   // k-half
  const int rrA = tid >> 4;         // 0..15: A row / B col

  // Empirical f64-MFMA D-layout probe (see R3): decode reg->row/col.
  int rowm[4], colm[4];
  {
    d4 dp = {0.0, 0.0, 0.0, 0.0};
    const double ap = (lane < 16) ? (double)(lane + 1) : (lane < 32 ? 1.0 : 0.0);
    const double bp = (lane < 16) ? 1.0
                    : (lane < 32 ? 1000.0 * (double)((lane & 15) + 1) : 0.0);
    dp = __builtin_amdgcn_mfma_f64_16x16x4f64(ap, bp, dp, 0, 0, 0);
    #pragma unroll
    for (int r = 0; r < 4; ++r) {
      const int iv = (int)(dp[r] + 0.5);
      rowm[r] = ((iv % 1000) - 1) & 15;
      colm[r] = ((iv / 1000) - 1) & 15;
    }
  }

  double pa[4];
  float4 pw0, pw1;
  const int c0 = rrA, c1 = 16 + rrA;
  const int wg0 = (c0 >> 3) * HDIM + hbase + (c0 & 7);
  const int wg1 = (c1 >> 3) * HDIM + hbase + (c1 & 7);

  auto load_to = [&](int ci) {
    const int kk = ci * 64 + khA * 32 + sA * 4;
    const int rr = r0 + rrA;
    if (kk < VDIM) {
      const float4 v = *(const float4*)(X + ((size_t)t * BBATCH + rr) * VDIM + kk);
      pa[0] = v.x; pa[1] = v.y; pa[2] = v.z; pa[3] = v.w;
    } else if (t == 0) {
      pa[0] = 0.0; pa[1] = 0.0; pa[2] = 0.0; pa[3] = 0.0;
    } else if (kk < VDIM + CDIM) {
      const double2 v0 = *(const double2*)(ybar + (size_t)rr * CDIM + (kk - VDIM));
      const double2 v1 = *(const double2*)(ybar + (size_t)rr * CDIM + (kk - VDIM) + 2);
      pa[0] = v0.x; pa[1] = v0.y; pa[2] = v1.x; pa[3] = v1.y;
    } else {
      const double2 v0 = *(const double2*)(hR + (size_t)rr * HDIM + (kk - 192));
      const double2 v1 = *(const double2*)(hR + (size_t)rr * HDIM + (kk - 192) + 2);
      pa[0] = v0.x; pa[1] = v0.y; pa[2] = v1.x; pa[3] = v1.y;
    }
    pw0 = (kk < 192) ? *(const float4*)(W_ih + (size_t)wg0 * 192 + kk)
                     : *(const float4*)(W_hh + (size_t)wg0 * HDIM + (kk - 192));
    pw1 = (kk < 192) ? *(const float4*)(W_ih + (size_t)wg1 * 192 + kk)
                     : *(const float4*)(W_hh + (size_t)wg1 * HDIM + (kk - 192));
  };
  auto store_to = [&](int buf) {
    #pragma unroll
    for (int j = 0; j < 4; ++j)
      aF[buf][khA][sA][16 * j + rrA] = pa[j];
    *(float4*)&bF[buf][khA][0][sA][rrA * 4] = pw0;
    *(float4*)&bF[buf][khA][1][sA][rrA * 4] = pw1;
  };

  const int ct = wid & 1, kh = wid >> 1;   // wave role
  d4 aa = {0.0, 0.0, 0.0, 0.0}, ab = aa;

  load_to(0);
  store_to(0);
  __syncthreads();

  for (int ci = 0; ci < NCHUNK; ++ci) {
    const int p = ci & 1;
    if (ci + 1 < NCHUNK) load_to(ci + 1);
    #pragma unroll
    for (int ss = 0; ss < 8; ++ss) {
      const double av = aF[p][kh][ss][lane];
      const double bv = (double)bF[p][kh][ct][ss][(lane & 15) * 4 + (lane >> 4)];
      if (ss & 1) ab = __builtin_amdgcn_mfma_f64_16x16x4f64(av, bv, ab, 0, 0, 0);
      else        aa = __builtin_amdgcn_mfma_f64_16x16x4f64(av, bv, aa, 0, 0, 0);
    }
    if (ci + 1 < NCHUNK) store_to(p ^ 1);
    __syncthreads();
  }
  const d4 acc = aa + ab;

  #pragma unroll
  for (int r = 0; r < 4; ++r)
    gsp[kh * 528 + rowm[r] * 33 + 16 * ct + colm[r]] = acc[r];
  __syncthreads();

  if (tid < 128) {
    const int jj = tid & 7, r = tid >> 3;
    const int g0 = hbase + jj;
    const double gi = gsp[r * 33 + jj]      + gsp[528 + r * 33 + jj]
                    + (double)b_ih[0 * HDIM + g0] + (double)b_hh[0 * HDIM + g0];
    const double gf = gsp[r * 33 + 8 + jj]  + gsp[528 + r * 33 + 8 + jj]
                    + (double)b_ih[1 * HDIM + g0] + (double)b_hh[1 * HDIM + g0];
    const double gg = gsp[r * 33 + 16 + jj] + gsp[528 + r * 33 + 16 + jj]
                    + (double)b_ih[2 * HDIM + g0] + (double)b_hh[2 * HDIM + g0];
    const double go = gsp[r * 33 + 24 + jj] + gsp[528 + r * 33 + 24 + jj]
                    + (double)b_ih[3 * HDIM + g0] + (double)b_hh[3 * HDIM + g0];
    const size_t oidx = (size_t)(r0 + r) * HDIM + g0;
    const double cold = (t == 0) ? 0.0 : cst[oidx];
    const double cn = sigd(gf) * cold + sigd(gi) * tanh(gg);
    const double hn = sigd(go) * tanh(cn);
    cst[oidx] = cn;
    hW[oidx]  = hn;
  }
}

// 256-thread phase-2 body (kept for the cooperative tail + final step).
__device__ __forceinline__ void phase2_body(
    const double* __restrict__ h, const float* __restrict__ wtro,
    const float* __restrict__ b_out, const float* __restrict__ wtrc,
    const float* __restrict__ b_ctrl, const float* __restrict__ noise,
    const int* __restrict__ epoch_p, double* __restrict__ ybar,
    double* __restrict__ preds, float* __restrict__ halt,
    double* __restrict__ ylast, int* __restrict__ rowlive,
    int* __restrict__ alive, int t, int b, int tid, double* sh)
{
  double* hsh = sh;          // 512
  double* p1  = hsh + HDIM;  // 256
  double* p2  = p1 + 256;    // 256
  double* ysh = p2 + 256;    // 64

  *(double2*)&hsh[2 * tid] = *(const double2*)(h + (size_t)b * HDIM + 2 * tid);
  __syncthreads();

  const int c = tid & 63, kq = tid >> 6;
  const int k0 = kq * 128;

  double s1 = 0.0, s2 = 0.0;
  #pragma unroll 8
  for (int k = k0; k < k0 + 128; ++k) {
    const double hk = hsh[k];
    s1 += hk * (double)wtro[k * 64 + c];
    s2 += hk * (double)wtrc[k * 64 + c];
  }
  p1[kq * 64 + c] = s1;
  p2[kq * 64 + c] = s2;
  __syncthreads();

  if (tid < 64)
    ysh[tid] = sigd(p1[tid] + p1[64 + tid] + p1[128 + tid] + p1[192 + tid]
                    + (double)b_out[tid]);
  __syncthreads();

  if (tid < 64) {
    double a2 = p2[tid] + p2[64 + tid] + p2[128 + tid] + p2[192 + tid];
    #pragma unroll 8
    for (int j = 0; j < CDIM; ++j)
      a2 += ysh[j] * (double)wtrc[(512 + j) * 64 + tid];
    a2 += (double)t * (double)wtrc[576 * 64 + tid] + (double)b_ctrl[tid];

    const double eps = exp(-7.0 * (double)(*epoch_p) / 99.0);
    const double pr  = (1.0 - eps) * sigd(a2) + eps * 0.05;
    const double n   = (double)noise[((size_t)t * BBATCH + b) * CDIM + tid];
    const bool   at  = n < pr;
    const double yh  = ysh[tid];
    const size_t i   = (size_t)b * CDIM + tid;

    const double pred_old = (t == 0) ? 0.0  : preds[i];
    const double ybar_old = (t == 0) ? 0.0  : ybar[i];
    const float  halt_old = (t == 0) ? -1.0f : halt[i];

    const double pred_new = (at && pred_old == 0.0) ? yh : pred_old;
    preds[i] = pred_new;
    ybar[i]  = (at && ybar_old == 0.0) ? 1.0 : ybar_old;
    halt[i]  = (halt_old == -1.0f && at) ? (float)t : halt_old;
    ylast[i] = yh;

    const unsigned long long m = __ballot(pred_new == 0.0);
    if (tid == 0) {
      rowlive[b] = (m != 0ull) ? 1 : 0;
      if (m != 0ull) atomicOr(alive + t, 1);
    }
  }
}

// ---------------- t < TSPLIT: 2-launch path ----------------

// Wide (MFMA) phase 1 with a narrow GEMV fast path when <= NTHRESH rows live.
__global__ __launch_bounds__(256, 4) void k_phase1(
    const float* __restrict__ X, const float* __restrict__ W_ih,
    const float* __restrict__ W_hh, const float* __restrict__ b_ih,
    const float* __restrict__ b_hh, const double* __restrict__ hR,
    double* __restrict__ hW, double* __restrict__ cst,
    const double* __restrict__ ybar, const int* __restrict__ rowlive,
    const int* __restrict__ nlive, const int* __restrict__ livelist, int t)
{
  const int tid = threadIdx.x, lane = tid & 63;
  const int cb = blockIdx.x, rb = blockIdx.y;
  const int bid = rb * 64 + cb;

  __shared__ __align__(16) double aF[2][2][8][66];
  __shared__ __align__(16) float  bF[2][2][2][8][68];

  if (t > 0) {
    const int L = nlive[t - 1];
    if (L == 0) return;                       // dead step

    if (L <= NTHRESH) {
      // ---------- narrow path: 256 blocks = (slot, hidden-chunk) ----------
      if (bid >= 256) return;
      const int s = bid >> 5, c = bid & 31;
      if (s >= L) return;
      const int r = livelist[(t - 1) * NTHRESH + s];

      double* A_lds = &aF[0][0][0][0];        // 704 doubles
      double* psum  = A_lds + 704;            // [kq][q][h16] = 256 doubles

      for (int k = tid; k < 704; k += 256) {
        double v;
        if (k < VDIM)       v = (double)X[((size_t)t * BBATCH + r) * VDIM + k];
        else if (k < 192)   v = ybar[(size_t)r * CDIM + (k - VDIM)];
        else                v = hR[(size_t)r * HDIM + (k - 192)];
        A_lds[k] = v;
      }
      __syncthreads();

      {
        const int h16 = tid & 15, q = (tid >> 4) & 3, kq = tid >> 6;
        const int gr = q * HDIM + c * 16 + h16;
        const int k0 = kq * 176, k1 = k0 + 176;
        double acc = 0.0;
        const int ihEnd = (k1 < 192) ? k1 : 192;
        #pragma unroll 4
        for (int k = k0; k < ihEnd; ++k)
          acc += A_lds[k] * (double)W_ih[(size_t)gr * 192 + k];
        const int hhBeg = (k0 > 192) ? k0 : 192;
        #pragma unroll 4
        for (int k = hhBeg; k < k1; ++k)
          acc += A_lds[k] * (double)W_hh[(size_t)gr * HDIM + (k - 192)];
        psum[kq * 64 + q * 16 + h16] = acc;
      }
      __syncthreads();

      if (tid < 16) {
        const int gid = c * 16 + tid;
        double g4[4];
        #pragma unroll
        for (int q = 0; q < 4; ++q)
          g4[q] = psum[q * 16 + tid] + psum[64 + q * 16 + tid]
                + psum[128 + q * 16 + tid] + psum[192 + q * 16 + tid]
                + (double)b_ih[q * HDIM + gid] + (double)b_hh[q * HDIM + gid];
        const size_t oidx = (size_t)r * HDIM + gid;
        const double cold = cst[oidx];
        const double cn = sigd(g4[1]) * cold + sigd(g4[0]) * tanh(g4[2]);
        const double hn = sigd(g4[3]) * tanh(cn);
        cst[oidx] = cn;
        hW[oidx]  = hn;
      }
      return;
    }

    // ---------- wide path: 16-row group skip ----------
    const unsigned long long m =
        __ballot((lane < 16) && (rowlive[rb * 16 + (lane & 15)] != 0));
    if (m == 0ull) return;
  }
  phase1_body(X, W_ih, W_hh, b_ih, b_hh, hR, hW, cst, ybar, t, cb, rb, tid, aF, bF);
}

// 512-thread phase 2 (R15-proven) + nlive/livelist maintenance.
__global__ __launch_bounds__(512) void k_phase2_512(
    const double* __restrict__ h, const float* __restrict__ wtro,
    const float* __restrict__ b_out, const float* __restrict__ wtrc,
    const float* __restrict__ b_ctrl, const float* __restrict__ noise,
    const int* __restrict__ epoch_p, double* __restrict__ ybar,
    double* __restrict__ preds, float* __restrict__ halt,
    double* __restrict__ ylast, int* __restrict__ rowlive,
    int* __restrict__ alive, int* __restrict__ nlive,
    int* __restrict__ livelist, int t)
{
  const int tid = threadIdx.x;
  const int b   = blockIdx.x;
  if (t > 0 && rowlive[b] == 0) return;

  __shared__ double hsh[HDIM];
  __shared__ double p1[8][64];
  __shared__ double p2[8][64];
  __shared__ double ysh[64];

  const int c = tid & 63, kq = tid >> 6;   // kq 0..7

  // issue halting-state + noise loads early; latency hides under the GEMV
  double pred_old = 0.0, ybar_old = 0.0, nse = 0.0;
  float  halt_old = -1.0f;
  if (tid < 64) {
    const size_t i = (size_t)b * CDIM + tid;
    if (t > 0) {
      pred_old = preds[i];
      ybar_old = ybar[i];
      halt_old = halt[i];
    }
    nse = (double)noise[((size_t)t * BBATCH + b) * CDIM + tid];
  }

  hsh[tid] = h[(size_t)b * HDIM + tid];
  __syncthreads();

  const int k0 = kq * 64;
  double s1 = 0.0, s2 = 0.0;
  #pragma unroll 8
  for (int k = k0; k < k0 + 64; ++k) {
    const double hk = hsh[k];
    s1 += hk * (double)wtro[k * 64 + c];
    s2 += hk * (double)wtrc[k * 64 + c];
  }
  p1[kq][c] = s1;
  p2[kq][c] = s2;
  __syncthreads();

  if (tid < 64)
    ysh[tid] = sigd(p1[0][tid] + p1[1][tid] + p1[2][tid] + p1[3][tid]
                  + p1[4][tid] + p1[5][tid] + p1[6][tid] + p1[7][tid]
                  + (double)b_out[tid]);
  __syncthreads();

  {  // controller partials: group kq handles j in [8kq, 8kq+8)
    double s3 = 0.0;
    #pragma unroll
    for (int j = kq * 8; j < kq * 8 + 8; ++j)
      s3 += ysh[j] * (double)wtrc[(512 + j) * 64 + c];
    p1[kq][c] = s3;
  }
  __syncthreads();

  if (tid < 64) {
    double a2 = (double)t * (double)wtrc[576 * 64 + tid] + (double)b_ctrl[tid];
    #pragma unroll
    for (int q = 0; q < 8; ++q)
      a2 += p2[q][tid] + p1[q][tid];

    const double eps = exp(-7.0 * (double)(*epoch_p) / 99.0);
    const double pr  = (1.0 - eps) * sigd(a2) + eps * 0.05;
    const bool   at  = nse < pr;
    const double yh  = ysh[tid];
    const size_t i   = (size_t)b * CDIM + tid;

    const double pred_new = (at && pred_old == 0.0) ? yh : pred_old;
    preds[i] = pred_new;
    ybar[i]  = (at && ybar_old == 0.0) ? 1.0 : ybar_old;
    halt[i]  = (halt_old == -1.0f && at) ? (float)t : halt_old;
    ylast[i] = yh;

    const unsigned long long m = __ballot(pred_new == 0.0);
    if (tid == 0) {
      rowlive[b] = (m != 0ull) ? 1 : 0;
      if (m != 0ull) {
        atomicOr(alive + t, 1);
        const int slot = atomicAdd(&nlive[t], 1);
        if (slot < NTHRESH) livelist[t * NTHRESH + slot] = b;
      }
    }
  }
}

// 256-thread phase 2 (final step)
__global__ __launch_bounds__(256) void k_phase2(
    const double* __restrict__ h, const float* __restrict__ wtro,
    const float* __restrict__ b_out, const float* __restrict__ wtrc,
    const float* __restrict__ b_ctrl, const float* __restrict__ noise,
    const int* __restrict__ epoch_p, double* __restrict__ ybar,
    double* __restrict__ preds, float* __restrict__ halt,
    double* __restrict__ ylast, int* __restrict__ rowlive,
    int* __restrict__ alive, int t)
{
  const int tid = threadIdx.x;
  const int b   = blockIdx.x;
  if (t > 0 && rowlive[b] == 0) return;
  __shared__ double sh[HDIM + 256 + 256 + 64];
  phase2_body(h, wtro, b_out, wtrc, b_ctrl, noise, epoch_p, ybar, preds, halt,
              ylast, rowlive, alive, t, b, tid, sh);
}

// ---------------- t >= TSPLIT: ONE cooperative tail kernel (R14-proven) ----------------
__global__ __launch_bounds__(256, 4) void k_tailloop(
    const float* __restrict__ X, const float* __restrict__ W_ih,
    const float* __restrict__ W_hh, const float* __restrict__ b_ih,
    const float* __restrict__ b_hh, const float* __restrict__ wtro,
    const float* __restrict__ b_out, const float* __restrict__ wtrc,
    const float* __restrict__ b_ctrl, const float* __restrict__ noise,
    const int* __restrict__ epoch_p, double* __restrict__ h0buf,
    double* __restrict__ h1buf, double* __restrict__ cst,
    double* __restrict__ ybar, double* __restrict__ preds,
    float* __restrict__ halt, double* __restrict__ ylast,
    int* __restrict__ rowlive, int* __restrict__ alive)
{
  cg::grid_group grid = cg::this_grid();
  const int tid  = threadIdx.x;
  const int lane = tid & 63;
  const int bid  = blockIdx.x;

  __shared__ __align__(16) double aF[2][2][8][66];
  __shared__ __align__(16) float  bF[2][2][2][8][68];

  for (int t = TSPLIT; t < TT; ++t) {
    if (__hip_atomic_load(&alive[t - 1], __ATOMIC_ACQUIRE,
                          __HIP_MEMORY_SCOPE_AGENT) == 0)
      return;   // uniform across grid; no sync crossed

    const double* hR = (t & 1) ? h1buf : h0buf;
    double*       hW = (t & 1) ? h0buf : h1buf;

    const int cb = bid & 63, rb = bid >> 6;
    const unsigned long long m =
        __ballot((lane < 16) && (rowlive[rb * 16 + (lane & 15)] != 0));
    if (m != 0ull)
      phase1_body(X, W_ih, W_hh, b_ih, b_hh, hR, hW, cst, ybar,
                  t, cb, rb, tid, aF, bF);
    grid.sync();

    if (bid < BBATCH && rowlive[bid] != 0)
      phase2_body(hW, wtro, b_out, wtrc, b_ctrl, noise, epoch_p, ybar, preds,
                  halt, ylast, rowlive, alive, t, bid, tid, &aF[0][0][0][0]);
    grid.sync();
  }
}

__global__ __launch_bounds__(256) void k_final_out(
    const double* __restrict__ preds, const double* __restrict__ ylast,
    float* __restrict__ out)
{
  const int i = blockIdx.x * 256 + threadIdx.x;
  const double p = preds[i];
  out[i] = (float)(p == 0.0 ? ylast[i] : p);
}

__global__ __launch_bounds__(256) void k_final_mean(
    const float* __restrict__ halt, float* __restrict__ out)
{
  __shared__ double s[256];
  double acc = 0.0;
  for (int i = threadIdx.x; i < BBATCH * CDIM; i += 256) {
    const float hp = halt[i];
    acc += 1.0 + (hp == -1.0f ? (double)(TT - 1) : (double)hp);
  }
  s[threadIdx.x] = acc;
  __syncthreads();
  for (int off = 128; off > 0; off >>= 1) {
    if (threadIdx.x < off) s[threadIdx.x] += s[threadIdx.x + off];
    __syncthreads();
  }
  if (threadIdx.x == 0)
    out[BBATCH * CDIM] = (float)(s[0] / (double)(BBATCH * CDIM) / (double)(TT + 1));
}

extern "C" void kernel_launch(void* const* d_in, const int* in_sizes, int n_in,
                              void* d_out, int out_size, void* d_ws, size_t ws_size,
                              hipStream_t stream)
{
  const float* X      = (const float*)d_in[0];
  const float* noise  = (const float*)d_in[1];
  const float* W_ih   = (const float*)d_in[2];
  const float* W_hh   = (const float*)d_in[3];
  const float* b_ih   = (const float*)d_in[4];
  const float* b_hh   = (const float*)d_in[5];
  const float* W_out  = (const float*)d_in[6];
  const float* b_out  = (const float*)d_in[7];
  const float* W_ctrl = (const float*)d_in[8];
  const float* b_ctrl = (const float*)d_in[9];
  const int*   epoch  = (const int*)d_in[10];
  float* out = (float*)d_out;

  char* ws = (char*)d_ws;
  double* h0       = (double*)ws;
  double* h1       = h0    + (size_t)BBATCH * HDIM;
  double* cst      = h1    + (size_t)BBATCH * HDIM;
  double* ybar     = cst   + (size_t)BBATCH * HDIM;
  double* preds    = ybar  + (size_t)BBATCH * CDIM;
  double* ylast    = preds + (size_t)BBATCH * CDIM;
  float*  halt     = (float*)(ylast + (size_t)BBATCH * CDIM);
  float*  wtro     = halt + (size_t)BBATCH * CDIM;
  float*  wtrc     = wtro + (size_t)HDIM * CDIM;
  int*    rowlive  = (int*)(wtrc + (size_t)577 * CDIM);
  int*    alive    = rowlive + BBATCH;
  int*    nlive    = alive + TT;
  int*    livelist = nlive + TT;

  k_init<<<145, 256, 0, stream>>>(wtro, W_out, wtrc, W_ctrl, rowlive, alive, nlive);

  for (int t = 0; t < TSPLIT; ++t) {
    const double* hR = (t & 1) ? h1 : h0;
    double*       hW = (t & 1) ? h0 : h1;
    k_phase1<<<dim3(64, 16), 256, 0, stream>>>(X, W_ih, W_hh, b_ih, b_hh,
                                               hR, hW, cst, ybar, rowlive,
                                               nlive, livelist, t);
    k_phase2_512<<<BBATCH, 512, 0, stream>>>(hW, wtro, b_out, wtrc, b_ctrl, noise,
                                             epoch, ybar, preds, halt, ylast,
                                             rowlive, alive, nlive, livelist, t);
  }

  {
    void* args[] = {
      (void*)&X, (void*)&W_ih, (void*)&W_hh, (void*)&b_ih, (void*)&b_hh,
      (void*)&wtro, (void*)&b_out, (void*)&wtrc, (void*)&b_ctrl, (void*)&noise,
      (void*)&epoch, (void*)&h0, (void*)&h1, (void*)&cst, (void*)&ybar,
      (void*)&preds, (void*)&halt, (void*)&ylast, (void*)&rowlive, (void*)&alive
    };
    hipLaunchCooperativeKernel((const void*)k_tailloop, dim3(1024), dim3(256),
                               args, 0, stream);
  }

  k_final_out<<<64, 256, 0, stream>>>(preds, ylast, out);
  k_final_mean<<<1, 256, 0, stream>>>(halt, out);
}

// Round 17
// 3756.228 us; speedup vs baseline: 1.0128x; 1.0128x over previous
//
#include <hip/hip_runtime.h>
#include <hip/hip_cooperative_groups.h>
#include <math.h>

#define TT 400
#define BBATCH 256
#define VDIM 128
#define CDIM 64
#define HDIM 512
#define NCHUNK 11    // 11 chunks x 64 k (2 k-halves of 32)
#define TSPLIT 176   // t >= TSPLIT handled by the single cooperative tail kernel

namespace cg = cooperative_groups;

typedef double d4 __attribute__((ext_vector_type(4)));

__device__ __forceinline__ double sigd(double x) {
  if (x >= 0.0) { double e = exp(-x); return 1.0 / (1.0 + e); }
  double e = exp(x); return e / (1.0 + e);
}

__global__ __launch_bounds__(256) void k_init(
    float* __restrict__ wtro, const float* __restrict__ W_out,
    float* __restrict__ wtrc, const float* __restrict__ W_ctrl,
    int* __restrict__ rowlive, int* __restrict__ alive)
{
  const int i = blockIdx.x * 256 + threadIdx.x;
  if (i < HDIM * CDIM) {
    const int k = i >> 6, c = i & 63;
    wtro[i] = W_out[c * HDIM + k];
  }
  if (i < 577 * CDIM) {
    const int k = i >> 6, c = i & 63;
    wtrc[i] = W_ctrl[c * 577 + k];
  }
  if (i < BBATCH) rowlive[i] = 1;
  if (i < TT) alive[i] = 0;
}

// ---------------- phase bodies ----------------

__device__ __forceinline__ void phase1_body(
    const float* __restrict__ X, const float* __restrict__ W_ih,
    const float* __restrict__ W_hh, const float* __restrict__ b_ih,
    const float* __restrict__ b_hh, const double* __restrict__ hR,
    double* __restrict__ hW, double* __restrict__ cst,
    const double* __restrict__ ybar, int t, int cb, int rb, int tid,
    double (*aF)[2][8][66], float (*bF)[2][2][8][68])
{
  const int lane = tid & 63;
  const int wid  = tid >> 6;
  const int r0   = rb * 16;
  const int hbase = cb * 8;

  double* gsp = &aF[0][0][0][0];   // gate staging aliases aF after the k-loop

  const int sA  = tid & 7;          // k-slot
  const int khA = (tid >> 3) & 1;   // k-half
  const int rrA = tid >> 4;         // 0..15: A row / B col

  // Empirical f64-MFMA D-layout probe (see R3): decode reg->row/col.
  int rowm[4], colm[4];
  {
    d4 dp = {0.0, 0.0, 0.0, 0.0};
    const double ap = (lane < 16) ? (double)(lane + 1) : (lane < 32 ? 1.0 : 0.0);
    const double bp = (lane < 16) ? 1.0
                    : (lane < 32 ? 1000.0 * (double)((lane & 15) + 1) : 0.0);
    dp = __builtin_amdgcn_mfma_f64_16x16x4f64(ap, bp, dp, 0, 0, 0);
    #pragma unroll
    for (int r = 0; r < 4; ++r) {
      const int iv = (int)(dp[r] + 0.5);
      rowm[r] = ((iv % 1000) - 1) & 15;
      colm[r] = ((iv / 1000) - 1) & 15;
    }
  }

  double pa[4];
  float4 pw0, pw1;
  const int c0 = rrA, c1 = 16 + rrA;
  const int wg0 = (c0 >> 3) * HDIM + hbase + (c0 & 7);
  const int wg1 = (c1 >> 3) * HDIM + hbase + (c1 & 7);

  auto load_to = [&](int ci) {
    const int kk = ci * 64 + khA * 32 + sA * 4;
    const int rr = r0 + rrA;
    if (kk < VDIM) {
      const float4 v = *(const float4*)(X + ((size_t)t * BBATCH + rr) * VDIM + kk);
      pa[0] = v.x; pa[1] = v.y; pa[2] = v.z; pa[3] = v.w;
    } else if (t == 0) {
      pa[0] = 0.0; pa[1] = 0.0; pa[2] = 0.0; pa[3] = 0.0;
    } else if (kk < VDIM + CDIM) {
      const double2 v0 = *(const double2*)(ybar + (size_t)rr * CDIM + (kk - VDIM));
      const double2 v1 = *(const double2*)(ybar + (size_t)rr * CDIM + (kk - VDIM) + 2);
      pa[0] = v0.x; pa[1] = v0.y; pa[2] = v1.x; pa[3] = v1.y;
    } else {
      const double2 v0 = *(const double2*)(hR + (size_t)rr * HDIM + (kk - 192));
      const double2 v1 = *(const double2*)(hR + (size_t)rr * HDIM + (kk - 192) + 2);
      pa[0] = v0.x; pa[1] = v0.y; pa[2] = v1.x; pa[3] = v1.y;
    }
    pw0 = (kk < 192) ? *(const float4*)(W_ih + (size_t)wg0 * 192 + kk)
                     : *(const float4*)(W_hh + (size_t)wg0 * HDIM + (kk - 192));
    pw1 = (kk < 192) ? *(const float4*)(W_ih + (size_t)wg1 * 192 + kk)
                     : *(const float4*)(W_hh + (size_t)wg1 * HDIM + (kk - 192));
  };
  auto store_to = [&](int buf) {
    #pragma unroll
    for (int j = 0; j < 4; ++j)
      aF[buf][khA][sA][16 * j + rrA] = pa[j];
    *(float4*)&bF[buf][khA][0][sA][rrA * 4] = pw0;
    *(float4*)&bF[buf][khA][1][sA][rrA * 4] = pw1;
  };

  const int ct = wid & 1, kh = wid >> 1;   // wave role
  d4 aa = {0.0, 0.0, 0.0, 0.0}, ab = aa;

  load_to(0);
  store_to(0);
  __syncthreads();

  for (int ci = 0; ci < NCHUNK; ++ci) {
    const int p = ci & 1;
    if (ci + 1 < NCHUNK) load_to(ci + 1);
    #pragma unroll
    for (int ss = 0; ss < 8; ++ss) {
      const double av = aF[p][kh][ss][lane];
      const double bv = (double)bF[p][kh][ct][ss][(lane & 15) * 4 + (lane >> 4)];
      if (ss & 1) ab = __builtin_amdgcn_mfma_f64_16x16x4f64(av, bv, ab, 0, 0, 0);
      else        aa = __builtin_amdgcn_mfma_f64_16x16x4f64(av, bv, aa, 0, 0, 0);
    }
    if (ci + 1 < NCHUNK) store_to(p ^ 1);
    __syncthreads();
  }
  const d4 acc = aa + ab;

  #pragma unroll
  for (int r = 0; r < 4; ++r)
    gsp[kh * 528 + rowm[r] * 33 + 16 * ct + colm[r]] = acc[r];
  __syncthreads();

  if (tid < 128) {
    const int jj = tid & 7, r = tid >> 3;
    const int g0 = hbase + jj;
    const double gi = gsp[r * 33 + jj]      + gsp[528 + r * 33 + jj]
                    + (double)b_ih[0 * HDIM + g0] + (double)b_hh[0 * HDIM + g0];
    const double gf = gsp[r * 33 + 8 + jj]  + gsp[528 + r * 33 + 8 + jj]
                    + (double)b_ih[1 * HDIM + g0] + (double)b_hh[1 * HDIM + g0];
    const double gg = gsp[r * 33 + 16 + jj] + gsp[528 + r * 33 + 16 + jj]
                    + (double)b_ih[2 * HDIM + g0] + (double)b_hh[2 * HDIM + g0];
    const double go = gsp[r * 33 + 24 + jj] + gsp[528 + r * 33 + 24 + jj]
                    + (double)b_ih[3 * HDIM + g0] + (double)b_hh[3 * HDIM + g0];
    const size_t oidx = (size_t)(r0 + r) * HDIM + g0;
    const double cold = (t == 0) ? 0.0 : cst[oidx];
    const double cn = sigd(gf) * cold + sigd(gi) * tanh(gg);
    const double hn = sigd(go) * tanh(cn);
    cst[oidx] = cn;
    hW[oidx]  = hn;
  }
}

// 256-thread phase-2 body (used by the cooperative tail).
__device__ __forceinline__ void phase2_body(
    const double* __restrict__ h, const float* __restrict__ wtro,
    const float* __restrict__ b_out, const float* __restrict__ wtrc,
    const float* __restrict__ b_ctrl, const float* __restrict__ noise,
    const int* __restrict__ epoch_p, double* __restrict__ ybar,
    double* __restrict__ preds, float* __restrict__ halt,
    double* __restrict__ ylast, int* __restrict__ rowlive,
    int* __restrict__ alive, int t, int b, int tid, double* sh)
{
  double* hsh = sh;          // 512
  double* p1  = hsh + HDIM;  // 256
  double* p2  = p1 + 256;    // 256
  double* ysh = p2 + 256;    // 64

  *(double2*)&hsh[2 * tid] = *(const double2*)(h + (size_t)b * HDIM + 2 * tid);
  __syncthreads();

  const int c = tid & 63, kq = tid >> 6;
  const int k0 = kq * 128;

  double s1 = 0.0, s2 = 0.0;
  #pragma unroll 8
  for (int k = k0; k < k0 + 128; ++k) {
    const double hk = hsh[k];
    s1 += hk * (double)wtro[k * 64 + c];
    s2 += hk * (double)wtrc[k * 64 + c];
  }
  p1[kq * 64 + c] = s1;
  p2[kq * 64 + c] = s2;
  __syncthreads();

  if (tid < 64)
    ysh[tid] = sigd(p1[tid] + p1[64 + tid] + p1[128 + tid] + p1[192 + tid]
                    + (double)b_out[tid]);
  __syncthreads();

  if (tid < 64) {
    double a2 = p2[tid] + p2[64 + tid] + p2[128 + tid] + p2[192 + tid];
    #pragma unroll 8
    for (int j = 0; j < CDIM; ++j)
      a2 += ysh[j] * (double)wtrc[(512 + j) * 64 + tid];
    a2 += (double)t * (double)wtrc[576 * 64 + tid] + (double)b_ctrl[tid];

    const double eps = exp(-7.0 * (double)(*epoch_p) / 99.0);
    const double pr  = (1.0 - eps) * sigd(a2) + eps * 0.05;
    const double n   = (double)noise[((size_t)t * BBATCH + b) * CDIM + tid];
    const bool   at  = n < pr;
    const double yh  = ysh[tid];
    const size_t i   = (size_t)b * CDIM + tid;

    const double pred_old = (t == 0) ? 0.0  : preds[i];
    const double ybar_old = (t == 0) ? 0.0  : ybar[i];
    const float  halt_old = (t == 0) ? -1.0f : halt[i];

    const double pred_new = (at && pred_old == 0.0) ? yh : pred_old;
    preds[i] = pred_new;
    ybar[i]  = (at && ybar_old == 0.0) ? 1.0 : ybar_old;
    halt[i]  = (halt_old == -1.0f && at) ? (float)t : halt_old;
    ylast[i] = yh;

    const unsigned long long m = __ballot(pred_new == 0.0);
    if (tid == 0) {
      rowlive[b] = (m != 0ull) ? 1 : 0;
      if (m != 0ull) atomicOr(alive + t, 1);
    }
  }
}

// ---------------- t < TSPLIT: 2-launch path ----------------

__global__ __launch_bounds__(256, 4) void k_phase1(
    const float* __restrict__ X, const float* __restrict__ W_ih,
    const float* __restrict__ W_hh, const float* __restrict__ b_ih,
    const float* __restrict__ b_hh, const double* __restrict__ hR,
    double* __restrict__ hW, double* __restrict__ cst,
    const double* __restrict__ ybar, const int* __restrict__ rowlive,
    const int* __restrict__ alive, int t)
{
  if (t > 0 && alive[t - 1] == 0) return;
  const int tid = threadIdx.x, lane = tid & 63;
  const int cb = blockIdx.x, rb = blockIdx.y;
  if (t > 0) {
    const unsigned long long m =
        __ballot((lane < 16) && (rowlive[rb * 16 + (lane & 15)] != 0));
    if (m == 0ull) return;
  }
  __shared__ __align__(16) double aF[2][2][8][66];
  __shared__ __align__(16) float  bF[2][2][2][8][68];
  phase1_body(X, W_ih, W_hh, b_ih, b_hh, hR, hW, cst, ybar, t, cb, rb, tid, aF, bF);
}

// 512-thread phase 2: K split 8-way, controller j-loop parallelized 8-way,
// halting-state loads hoisted above the GEMV (R15-proven).
__global__ __launch_bounds__(512) void k_phase2_512(
    const double* __restrict__ h, const float* __restrict__ wtro,
    const float* __restrict__ b_out, const float* __restrict__ wtrc,
    const float* __restrict__ b_ctrl, const float* __restrict__ noise,
    const int* __restrict__ epoch_p, double* __restrict__ ybar,
    double* __restrict__ preds, float* __restrict__ halt,
    double* __restrict__ ylast, int* __restrict__ rowlive,
    int* __restrict__ alive, int t)
{
  const int tid = threadIdx.x;
  const int b   = blockIdx.x;
  if (t > 0 && rowlive[b] == 0) return;

  __shared__ double hsh[HDIM];
  __shared__ double p1[8][64];
  __shared__ double p2[8][64];
  __shared__ double ysh[64];

  const int c = tid & 63, kq = tid >> 6;   // kq 0..7

  // issue halting-state + noise loads early; latency hides under the GEMV
  double pred_old = 0.0, ybar_old = 0.0, nse = 0.0;
  float  halt_old = -1.0f;
  if (tid < 64) {
    const size_t i = (size_t)b * CDIM + tid;
    if (t > 0) {
      pred_old = preds[i];
      ybar_old = ybar[i];
      halt_old = halt[i];
    }
    nse = (double)noise[((size_t)t * BBATCH + b) * CDIM + tid];
  }

  hsh[tid] = h[(size_t)b * HDIM + tid];
  __syncthreads();

  const int k0 = kq * 64;
  double s1 = 0.0, s2 = 0.0;
  #pragma unroll 8
  for (int k = k0; k < k0 + 64; ++k) {
    const double hk = hsh[k];
    s1 += hk * (double)wtro[k * 64 + c];
    s2 += hk * (double)wtrc[k * 64 + c];
  }
  p1[kq][c] = s1;
  p2[kq][c] = s2;
  __syncthreads();

  if (tid < 64)
    ysh[tid] = sigd(p1[0][tid] + p1[1][tid] + p1[2][tid] + p1[3][tid]
                  + p1[4][tid] + p1[5][tid] + p1[6][tid] + p1[7][tid]
                  + (double)b_out[tid]);
  __syncthreads();

  {  // controller partials: group kq handles j in [8kq, 8kq+8)
    double s3 = 0.0;
    #pragma unroll
    for (int j = kq * 8; j < kq * 8 + 8; ++j)
      s3 += ysh[j] * (double)wtrc[(512 + j) * 64 + c];
    p1[kq][c] = s3;
  }
  __syncthreads();

  if (tid < 64) {
    double a2 = (double)t * (double)wtrc[576 * 64 + tid] + (double)b_ctrl[tid];
    #pragma unroll
    for (int q = 0; q < 8; ++q)
      a2 += p2[q][tid] + p1[q][tid];

    const double eps = exp(-7.0 * (double)(*epoch_p) / 99.0);
    const double pr  = (1.0 - eps) * sigd(a2) + eps * 0.05;
    const bool   at  = nse < pr;
    const double yh  = ysh[tid];
    const size_t i   = (size_t)b * CDIM + tid;

    const double pred_new = (at && pred_old == 0.0) ? yh : pred_old;
    preds[i] = pred_new;
    ybar[i]  = (at && ybar_old == 0.0) ? 1.0 : ybar_old;
    halt[i]  = (halt_old == -1.0f && at) ? (float)t : halt_old;
    ylast[i] = yh;

    const unsigned long long m = __ballot(pred_new == 0.0);
    if (tid == 0) {
      rowlive[b] = (m != 0ull) ? 1 : 0;
      if (m != 0ull) atomicOr(alive + t, 1);
    }
  }
}

// ---------------- t >= TSPLIT: ONE cooperative tail kernel (R14-proven) ----------------
__global__ __launch_bounds__(256, 4) void k_tailloop(
    const float* __restrict__ X, const float* __restrict__ W_ih,
    const float* __restrict__ W_hh, const float* __restrict__ b_ih,
    const float* __restrict__ b_hh, const float* __restrict__ wtro,
    const float* __restrict__ b_out, const float* __restrict__ wtrc,
    const float* __restrict__ b_ctrl, const float* __restrict__ noise,
    const int* __restrict__ epoch_p, double* __restrict__ h0buf,
    double* __restrict__ h1buf, double* __restrict__ cst,
    double* __restrict__ ybar, double* __restrict__ preds,
    float* __restrict__ halt, double* __restrict__ ylast,
    int* __restrict__ rowlive, int* __restrict__ alive)
{
  cg::grid_group grid = cg::this_grid();
  const int tid  = threadIdx.x;
  const int lane = tid & 63;
  const int bid  = blockIdx.x;

  __shared__ __align__(16) double aF[2][2][8][66];
  __shared__ __align__(16) float  bF[2][2][2][8][68];

  for (int t = TSPLIT; t < TT; ++t) {
    if (__hip_atomic_load(&alive[t - 1], __ATOMIC_ACQUIRE,
                          __HIP_MEMORY_SCOPE_AGENT) == 0)
      return;   // uniform across grid; no sync crossed

    const double* hR = (t & 1) ? h1buf : h0buf;
    double*       hW = (t & 1) ? h0buf : h1buf;

    const int cb = bid & 63, rb = bid >> 6;
    const unsigned long long m =
        __ballot((lane < 16) && (rowlive[rb * 16 + (lane & 15)] != 0));
    if (m != 0ull)
      phase1_body(X, W_ih, W_hh, b_ih, b_hh, hR, hW, cst, ybar,
                  t, cb, rb, tid, aF, bF);
    grid.sync();

    if (bid < BBATCH && rowlive[bid] != 0)
      phase2_body(hW, wtro, b_out, wtrc, b_ctrl, noise, epoch_p, ybar, preds,
                  halt, ylast, rowlive, alive, t, bid, tid, &aF[0][0][0][0]);
    grid.sync();
  }
}

__global__ __launch_bounds__(256) void k_final_out(
    const double* __restrict__ preds, const double* __restrict__ ylast,
    float* __restrict__ out)
{
  const int i = blockIdx.x * 256 + threadIdx.x;
  const double p = preds[i];
  out[i] = (float)(p == 0.0 ? ylast[i] : p);
}

__global__ __launch_bounds__(256) void k_final_mean(
    const float* __restrict__ halt, float* __restrict__ out)
{
  __shared__ double s[256];
  double acc = 0.0;
  for (int i = threadIdx.x; i < BBATCH * CDIM; i += 256) {
    const float hp = halt[i];
    acc += 1.0 + (hp == -1.0f ? (double)(TT - 1) : (double)hp);
  }
  s[threadIdx.x] = acc;
  __syncthreads();
  for (int off = 128; off > 0; off >>= 1) {
    if (threadIdx.x < off) s[threadIdx.x] += s[threadIdx.x + off];
    __syncthreads();
  }
  if (threadIdx.x == 0)
    out[BBATCH * CDIM] = (float)(s[0] / (double)(BBATCH * CDIM) / (double)(TT + 1));
}

extern "C" void kernel_launch(void* const* d_in, const int* in_sizes, int n_in,
                              void* d_out, int out_size, void* d_ws, size_t ws_size,
                              hipStream_t stream)
{
  const float* X      = (const float*)d_in[0];
  const float* noise  = (const float*)d_in[1];
  const float* W_ih   = (const float*)d_in[2];
  const float* W_hh   = (const float*)d_in[3];
  const float* b_ih   = (const float*)d_in[4];
  const float* b_hh   = (const float*)d_in[5];
  const float* W_out  = (const float*)d_in[6];
  const float* b_out  = (const float*)d_in[7];
  const float* W_ctrl = (const float*)d_in[8];
  const float* b_ctrl = (const float*)d_in[9];
  const int*   epoch  = (const int*)d_in[10];
  float* out = (float*)d_out;

  char* ws = (char*)d_ws;
  double* h0      = (double*)ws;
  double* h1      = h0    + (size_t)BBATCH * HDIM;
  double* cst     = h1    + (size_t)BBATCH * HDIM;
  double* ybar    = cst   + (size_t)BBATCH * HDIM;
  double* preds   = ybar  + (size_t)BBATCH * CDIM;
  double* ylast   = preds + (size_t)BBATCH * CDIM;
  float*  halt    = (float*)(ylast + (size_t)BBATCH * CDIM);
  float*  wtro    = halt + (size_t)BBATCH * CDIM;
  float*  wtrc    = wtro + (size_t)HDIM * CDIM;
  int*    rowlive = (int*)(wtrc + (size_t)577 * CDIM);
  int*    alive   = rowlive + BBATCH;

  k_init<<<145, 256, 0, stream>>>(wtro, W_out, wtrc, W_ctrl, rowlive, alive);

  for (int t = 0; t < TSPLIT; ++t) {
    const double* hR = (t & 1) ? h1 : h0;
    double*       hW = (t & 1) ? h0 : h1;
    k_phase1<<<dim3(64, 16), 256, 0, stream>>>(X, W_ih, W_hh, b_ih, b_hh,
                                               hR, hW, cst, ybar, rowlive, alive, t);
    k_phase2_512<<<BBATCH, 512, 0, stream>>>(hW, wtro, b_out, wtrc, b_ctrl, noise,
                                             epoch, ybar, preds, halt, ylast,
                                             rowlive, alive, t);
  }

  {
    void* args[] = {
      (void*)&X, (void*)&W_ih, (void*)&W_hh, (void*)&b_ih, (void*)&b_hh,
      (void*)&wtro, (void*)&b_out, (void*)&wtrc, (void*)&b_ctrl, (void*)&noise,
      (void*)&epoch, (void*)&h0, (void*)&h1, (void*)&cst, (void*)&ybar,
      (void*)&preds, (void*)&halt, (void*)&ylast, (void*)&rowlive, (void*)&alive
    };
    hipLaunchCooperativeKernel((const void*)k_tailloop, dim3(1024), dim3(256),
                               args, 0, stream);
  }

  k_final_out<<<64, 256, 0, stream>>>(preds, ylast, out);
  k_final_mean<<<1, 256, 0, stream>>>(halt, out);
}

// Round 18
// 3537.600 us; speedup vs baseline: 1.0754x; 1.0618x over previous
//
#include <hip/hip_runtime.h>
#include <hip/hip_cooperative_groups.h>
#include <math.h>

#define TT 400
#define BBATCH 256
#define VDIM 128
#define CDIM 64
#define HDIM 512
#define NCHUNK 11    // 11 chunks x 64 k (2 k-halves of 32)
#define TSPLIT 160   // t >= TSPLIT handled by the single cooperative tail kernel

namespace cg = cooperative_groups;

typedef double d4 __attribute__((ext_vector_type(4)));

__device__ __forceinline__ double sigd(double x) {
  if (x >= 0.0) { double e = exp(-x); return 1.0 / (1.0 + e); }
  double e = exp(x); return e / (1.0 + e);
}

__global__ __launch_bounds__(256) void k_init(
    float* __restrict__ wtro, const float* __restrict__ W_out,
    float* __restrict__ wtrc, const float* __restrict__ W_ctrl,
    int* __restrict__ rowlive, int* __restrict__ alive)
{
  const int i = blockIdx.x * 256 + threadIdx.x;
  if (i < HDIM * CDIM) {
    const int k = i >> 6, c = i & 63;
    wtro[i] = W_out[c * HDIM + k];
  }
  if (i < 577 * CDIM) {
    const int k = i >> 6, c = i & 63;
    wtrc[i] = W_ctrl[c * 577 + k];
  }
  if (i < BBATCH) rowlive[i] = 1;
  if (i < TT) alive[i] = 0;
}

// ---------------- phase bodies ----------------

__device__ __forceinline__ void phase1_body(
    const float* __restrict__ X, const float* __restrict__ W_ih,
    const float* __restrict__ W_hh, const float* __restrict__ b_ih,
    const float* __restrict__ b_hh, const double* __restrict__ hR,
    double* __restrict__ hW, double* __restrict__ cst,
    const double* __restrict__ ybar, int t, int cb, int rb, int tid,
    double (*aF)[2][8][66], float (*bF)[2][2][8][68])
{
  const int lane = tid & 63;
  const int wid  = tid >> 6;
  const int r0   = rb * 16;
  const int hbase = cb * 8;

  double* gsp = &aF[0][0][0][0];   // gate staging aliases aF after the k-loop

  const int sA  = tid & 7;          // k-slot
  const int khA = (tid >> 3) & 1;   // k-half
  const int rrA = tid >> 4;         // 0..15: A row / B col

  // Empirical f64-MFMA D-layout probe (see R3): decode reg->row/col.
  int rowm[4], colm[4];
  {
    d4 dp = {0.0, 0.0, 0.0, 0.0};
    const double ap = (lane < 16) ? (double)(lane + 1) : (lane < 32 ? 1.0 : 0.0);
    const double bp = (lane < 16) ? 1.0
                    : (lane < 32 ? 1000.0 * (double)((lane & 15) + 1) : 0.0);
    dp = __builtin_amdgcn_mfma_f64_16x16x4f64(ap, bp, dp, 0, 0, 0);
    #pragma unroll
    for (int r = 0; r < 4; ++r) {
      const int iv = (int)(dp[r] + 0.5);
      rowm[r] = ((iv % 1000) - 1) & 15;
      colm[r] = ((iv / 1000) - 1) & 15;
    }
  }

  double pa[4];
  float4 pw0, pw1;
  const int c0 = rrA, c1 = 16 + rrA;
  const int wg0 = (c0 >> 3) * HDIM + hbase + (c0 & 7);
  const int wg1 = (c1 >> 3) * HDIM + hbase + (c1 & 7);

  auto load_to = [&](int ci) {
    const int kk = ci * 64 + khA * 32 + sA * 4;
    const int rr = r0 + rrA;
    if (kk < VDIM) {
      const float4 v = *(const float4*)(X + ((size_t)t * BBATCH + rr) * VDIM + kk);
      pa[0] = v.x; pa[1] = v.y; pa[2] = v.z; pa[3] = v.w;
    } else if (t == 0) {
      pa[0] = 0.0; pa[1] = 0.0; pa[2] = 0.0; pa[3] = 0.0;
    } else if (kk < VDIM + CDIM) {
      const double2 v0 = *(const double2*)(ybar + (size_t)rr * CDIM + (kk - VDIM));
      const double2 v1 = *(const double2*)(ybar + (size_t)rr * CDIM + (kk - VDIM) + 2);
      pa[0] = v0.x; pa[1] = v0.y; pa[2] = v1.x; pa[3] = v1.y;
    } else {
      const double2 v0 = *(const double2*)(hR + (size_t)rr * HDIM + (kk - 192));
      const double2 v1 = *(const double2*)(hR + (size_t)rr * HDIM + (kk - 192) + 2);
      pa[0] = v0.x; pa[1] = v0.y; pa[2] = v1.x; pa[3] = v1.y;
    }
    pw0 = (kk < 192) ? *(const float4*)(W_ih + (size_t)wg0 * 192 + kk)
                     : *(const float4*)(W_hh + (size_t)wg0 * HDIM + (kk - 192));
    pw1 = (kk < 192) ? *(const float4*)(W_ih + (size_t)wg1 * 192 + kk)
                     : *(const float4*)(W_hh + (size_t)wg1 * HDIM + (kk - 192));
  };
  auto store_to = [&](int buf) {
    #pragma unroll
    for (int j = 0; j < 4; ++j)
      aF[buf][khA][sA][16 * j + rrA] = pa[j];
    *(float4*)&bF[buf][khA][0][sA][rrA * 4] = pw0;
    *(float4*)&bF[buf][khA][1][sA][rrA * 4] = pw1;
  };

  const int ct = wid & 1, kh = wid >> 1;   // wave role
  d4 aa = {0.0, 0.0, 0.0, 0.0}, ab = aa;

  load_to(0);
  store_to(0);
  __syncthreads();

  for (int ci = 0; ci < NCHUNK; ++ci) {
    const int p = ci & 1;
    if (ci + 1 < NCHUNK) load_to(ci + 1);
    #pragma unroll
    for (int ss = 0; ss < 8; ++ss) {
      const double av = aF[p][kh][ss][lane];
      const double bv = (double)bF[p][kh][ct][ss][(lane & 15) * 4 + (lane >> 4)];
      if (ss & 1) ab = __builtin_amdgcn_mfma_f64_16x16x4f64(av, bv, ab, 0, 0, 0);
      else        aa = __builtin_amdgcn_mfma_f64_16x16x4f64(av, bv, aa, 0, 0, 0);
    }
    if (ci + 1 < NCHUNK) store_to(p ^ 1);
    __syncthreads();
  }
  const d4 acc = aa + ab;

  #pragma unroll
  for (int r = 0; r < 4; ++r)
    gsp[kh * 528 + rowm[r] * 33 + 16 * ct + colm[r]] = acc[r];
  __syncthreads();

  if (tid < 128) {
    const int jj = tid & 7, r = tid >> 3;
    const int g0 = hbase + jj;
    const double gi = gsp[r * 33 + jj]      + gsp[528 + r * 33 + jj]
                    + (double)b_ih[0 * HDIM + g0] + (double)b_hh[0 * HDIM + g0];
    const double gf = gsp[r * 33 + 8 + jj]  + gsp[528 + r * 33 + 8 + jj]
                    + (double)b_ih[1 * HDIM + g0] + (double)b_hh[1 * HDIM + g0];
    const double gg = gsp[r * 33 + 16 + jj] + gsp[528 + r * 33 + 16 + jj]
                    + (double)b_ih[2 * HDIM + g0] + (double)b_hh[2 * HDIM + g0];
    const double go = gsp[r * 33 + 24 + jj] + gsp[528 + r * 33 + 24 + jj]
                    + (double)b_ih[3 * HDIM + g0] + (double)b_hh[3 * HDIM + g0];
    const size_t oidx = (size_t)(r0 + r) * HDIM + g0;
    const double cold = (t == 0) ? 0.0 : cst[oidx];
    const double cn = sigd(gf) * cold + sigd(gi) * tanh(gg);
    const double hn = sigd(go) * tanh(cn);
    cst[oidx] = cn;
    hW[oidx]  = hn;
  }
}

// 256-thread phase-2 body (used by the cooperative tail).
__device__ __forceinline__ void phase2_body(
    const double* __restrict__ h, const float* __restrict__ wtro,
    const float* __restrict__ b_out, const float* __restrict__ wtrc,
    const float* __restrict__ b_ctrl, const float* __restrict__ noise,
    const int* __restrict__ epoch_p, double* __restrict__ ybar,
    double* __restrict__ preds, float* __restrict__ halt,
    double* __restrict__ ylast, int* __restrict__ rowlive,
    int* __restrict__ alive, int t, int b, int tid, double* sh)
{
  double* hsh = sh;          // 512
  double* p1  = hsh + HDIM;  // 256
  double* p2  = p1 + 256;    // 256
  double* ysh = p2 + 256;    // 64

  *(double2*)&hsh[2 * tid] = *(const double2*)(h + (size_t)b * HDIM + 2 * tid);
  __syncthreads();

  const int c = tid & 63, kq = tid >> 6;
  const int k0 = kq * 128;

  double s1 = 0.0, s2 = 0.0;
  #pragma unroll 8
  for (int k = k0; k < k0 + 128; ++k) {
    const double hk = hsh[k];
    s1 += hk * (double)wtro[k * 64 + c];
    s2 += hk * (double)wtrc[k * 64 + c];
  }
  p1[kq * 64 + c] = s1;
  p2[kq * 64 + c] = s2;
  __syncthreads();

  if (tid < 64)
    ysh[tid] = sigd(p1[tid] + p1[64 + tid] + p1[128 + tid] + p1[192 + tid]
                    + (double)b_out[tid]);
  __syncthreads();

  if (tid < 64) {
    double a2 = p2[tid] + p2[64 + tid] + p2[128 + tid] + p2[192 + tid];
    #pragma unroll 8
    for (int j = 0; j < CDIM; ++j)
      a2 += ysh[j] * (double)wtrc[(512 + j) * 64 + tid];
    a2 += (double)t * (double)wtrc[576 * 64 + tid] + (double)b_ctrl[tid];

    const double eps = exp(-7.0 * (double)(*epoch_p) / 99.0);
    const double pr  = (1.0 - eps) * sigd(a2) + eps * 0.05;
    const double n   = (double)noise[((size_t)t * BBATCH + b) * CDIM + tid];
    const bool   at  = n < pr;
    const double yh  = ysh[tid];
    const size_t i   = (size_t)b * CDIM + tid;

    const double pred_old = (t == 0) ? 0.0  : preds[i];
    const double ybar_old = (t == 0) ? 0.0  : ybar[i];
    const float  halt_old = (t == 0) ? -1.0f : halt[i];

    const double pred_new = (at && pred_old == 0.0) ? yh : pred_old;
    preds[i] = pred_new;
    ybar[i]  = (at && ybar_old == 0.0) ? 1.0 : ybar_old;
    halt[i]  = (halt_old == -1.0f && at) ? (float)t : halt_old;
    ylast[i] = yh;

    const unsigned long long m = __ballot(pred_new == 0.0);
    if (tid == 0) {
      rowlive[b] = (m != 0ull) ? 1 : 0;
      if (m != 0ull) atomicOr(alive + t, 1);
    }
  }
}

// ---------------- t < TSPLIT: 2-launch path ----------------

__global__ __launch_bounds__(256, 4) void k_phase1(
    const float* __restrict__ X, const float* __restrict__ W_ih,
    const float* __restrict__ W_hh, const float* __restrict__ b_ih,
    const float* __restrict__ b_hh, const double* __restrict__ hR,
    double* __restrict__ hW, double* __restrict__ cst,
    const double* __restrict__ ybar, const int* __restrict__ rowlive,
    const int* __restrict__ alive, int t)
{
  if (t > 0 && alive[t - 1] == 0) return;
  const int tid = threadIdx.x, lane = tid & 63;
  const int cb = blockIdx.x, rb = blockIdx.y;
  if (t > 0) {
    const unsigned long long m =
        __ballot((lane < 16) && (rowlive[rb * 16 + (lane & 15)] != 0));
    if (m == 0ull) return;
  }
  __shared__ __align__(16) double aF[2][2][8][66];
  __shared__ __align__(16) float  bF[2][2][2][8][68];
  phase1_body(X, W_ih, W_hh, b_ih, b_hh, hR, hW, cst, ybar, t, cb, rb, tid, aF, bF);
}

// 512-thread phase 2: K split 8-way, controller j-loop parallelized 8-way,
// halting-state loads hoisted above the GEMV (R15-proven).
__global__ __launch_bounds__(512) void k_phase2_512(
    const double* __restrict__ h, const float* __restrict__ wtro,
    const float* __restrict__ b_out, const float* __restrict__ wtrc,
    const float* __restrict__ b_ctrl, const float* __restrict__ noise,
    const int* __restrict__ epoch_p, double* __restrict__ ybar,
    double* __restrict__ preds, float* __restrict__ halt,
    double* __restrict__ ylast, int* __restrict__ rowlive,
    int* __restrict__ alive, int t)
{
  const int tid = threadIdx.x;
  const int b   = blockIdx.x;
  if (t > 0 && rowlive[b] == 0) return;

  __shared__ double hsh[HDIM];
  __shared__ double p1[8][64];
  __shared__ double p2[8][64];
  __shared__ double ysh[64];

  const int c = tid & 63, kq = tid >> 6;   // kq 0..7

  // issue halting-state + noise loads early; latency hides under the GEMV
  double pred_old = 0.0, ybar_old = 0.0, nse = 0.0;
  float  halt_old = -1.0f;
  if (tid < 64) {
    const size_t i = (size_t)b * CDIM + tid;
    if (t > 0) {
      pred_old = preds[i];
      ybar_old = ybar[i];
      halt_old = halt[i];
    }
    nse = (double)noise[((size_t)t * BBATCH + b) * CDIM + tid];
  }

  hsh[tid] = h[(size_t)b * HDIM + tid];
  __syncthreads();

  const int k0 = kq * 64;
  double s1 = 0.0, s2 = 0.0;
  #pragma unroll 8
  for (int k = k0; k < k0 + 64; ++k) {
    const double hk = hsh[k];
    s1 += hk * (double)wtro[k * 64 + c];
    s2 += hk * (double)wtrc[k * 64 + c];
  }
  p1[kq][c] = s1;
  p2[kq][c] = s2;
  __syncthreads();

  if (tid < 64)
    ysh[tid] = sigd(p1[0][tid] + p1[1][tid] + p1[2][tid] + p1[3][tid]
                  + p1[4][tid] + p1[5][tid] + p1[6][tid] + p1[7][tid]
                  + (double)b_out[tid]);
  __syncthreads();

  {  // controller partials: group kq handles j in [8kq, 8kq+8)
    double s3 = 0.0;
    #pragma unroll
    for (int j = kq * 8; j < kq * 8 + 8; ++j)
      s3 += ysh[j] * (double)wtrc[(512 + j) * 64 + c];
    p1[kq][c] = s3;
  }
  __syncthreads();

  if (tid < 64) {
    double a2 = (double)t * (double)wtrc[576 * 64 + tid] + (double)b_ctrl[tid];
    #pragma unroll
    for (int q = 0; q < 8; ++q)
      a2 += p2[q][tid] + p1[q][tid];

    const double eps = exp(-7.0 * (double)(*epoch_p) / 99.0);
    const double pr  = (1.0 - eps) * sigd(a2) + eps * 0.05;
    const bool   at  = nse < pr;
    const double yh  = ysh[tid];
    const size_t i   = (size_t)b * CDIM + tid;

    const double pred_new = (at && pred_old == 0.0) ? yh : pred_old;
    preds[i] = pred_new;
    ybar[i]  = (at && ybar_old == 0.0) ? 1.0 : ybar_old;
    halt[i]  = (halt_old == -1.0f && at) ? (float)t : halt_old;
    ylast[i] = yh;

    const unsigned long long m = __ballot(pred_new == 0.0);
    if (tid == 0) {
      rowlive[b] = (m != 0ull) ? 1 : 0;
      if (m != 0ull) atomicOr(alive + t, 1);
    }
  }
}

// ---------------- t >= TSPLIT: ONE cooperative tail kernel (R14-proven) ----------------
__global__ __launch_bounds__(256, 4) void k_tailloop(
    const float* __restrict__ X, const float* __restrict__ W_ih,
    const float* __restrict__ W_hh, const float* __restrict__ b_ih,
    const float* __restrict__ b_hh, const float* __restrict__ wtro,
    const float* __restrict__ b_out, const float* __restrict__ wtrc,
    const float* __restrict__ b_ctrl, const float* __restrict__ noise,
    const int* __restrict__ epoch_p, double* __restrict__ h0buf,
    double* __restrict__ h1buf, double* __restrict__ cst,
    double* __restrict__ ybar, double* __restrict__ preds,
    float* __restrict__ halt, double* __restrict__ ylast,
    int* __restrict__ rowlive, int* __restrict__ alive)
{
  cg::grid_group grid = cg::this_grid();
  const int tid  = threadIdx.x;
  const int lane = tid & 63;
  const int bid  = blockIdx.x;

  __shared__ __align__(16) double aF[2][2][8][66];
  __shared__ __align__(16) float  bF[2][2][2][8][68];

  for (int t = TSPLIT; t < TT; ++t) {
    if (__hip_atomic_load(&alive[t - 1], __ATOMIC_ACQUIRE,
                          __HIP_MEMORY_SCOPE_AGENT) == 0)
      return;   // uniform across grid; no sync crossed

    const double* hR = (t & 1) ? h1buf : h0buf;
    double*       hW = (t & 1) ? h0buf : h1buf;

    const int cb = bid & 63, rb = bid >> 6;
    const unsigned long long m =
        __ballot((lane < 16) && (rowlive[rb * 16 + (lane & 15)] != 0));
    if (m != 0ull)
      phase1_body(X, W_ih, W_hh, b_ih, b_hh, hR, hW, cst, ybar,
                  t, cb, rb, tid, aF, bF);
    grid.sync();

    if (bid < BBATCH && rowlive[bid] != 0)
      phase2_body(hW, wtro, b_out, wtrc, b_ctrl, noise, epoch_p, ybar, preds,
                  halt, ylast, rowlive, alive, t, bid, tid, &aF[0][0][0][0]);
    grid.sync();
  }
}

__global__ __launch_bounds__(256) void k_final_out(
    const double* __restrict__ preds, const double* __restrict__ ylast,
    float* __restrict__ out)
{
  const int i = blockIdx.x * 256 + threadIdx.x;
  const double p = preds[i];
  out[i] = (float)(p == 0.0 ? ylast[i] : p);
}

__global__ __launch_bounds__(256) void k_final_mean(
    const float* __restrict__ halt, float* __restrict__ out)
{
  __shared__ double s[256];
  double acc = 0.0;
  for (int i = threadIdx.x; i < BBATCH * CDIM; i += 256) {
    const float hp = halt[i];
    acc += 1.0 + (hp == -1.0f ? (double)(TT - 1) : (double)hp);
  }
  s[threadIdx.x] = acc;
  __syncthreads();
  for (int off = 128; off > 0; off >>= 1) {
    if (threadIdx.x < off) s[threadIdx.x] += s[threadIdx.x + off];
    __syncthreads();
  }
  if (threadIdx.x == 0)
    out[BBATCH * CDIM] = (float)(s[0] / (double)(BBATCH * CDIM) / (double)(TT + 1));
}

extern "C" void kernel_launch(void* const* d_in, const int* in_sizes, int n_in,
                              void* d_out, int out_size, void* d_ws, size_t ws_size,
                              hipStream_t stream)
{
  const float* X      = (const float*)d_in[0];
  const float* noise  = (const float*)d_in[1];
  const float* W_ih   = (const float*)d_in[2];
  const float* W_hh   = (const float*)d_in[3];
  const float* b_ih   = (const float*)d_in[4];
  const float* b_hh   = (const float*)d_in[5];
  const float* W_out  = (const float*)d_in[6];
  const float* b_out  = (const float*)d_in[7];
  const float* W_ctrl = (const float*)d_in[8];
  const float* b_ctrl = (const float*)d_in[9];
  const int*   epoch  = (const int*)d_in[10];
  float* out = (float*)d_out;

  char* ws = (char*)d_ws;
  double* h0      = (double*)ws;
  double* h1      = h0    + (size_t)BBATCH * HDIM;
  double* cst     = h1    + (size_t)BBATCH * HDIM;
  double* ybar    = cst   + (size_t)BBATCH * HDIM;
  double* preds   = ybar  + (size_t)BBATCH * CDIM;
  double* ylast   = preds + (size_t)BBATCH * CDIM;
  float*  halt    = (float*)(ylast + (size_t)BBATCH * CDIM);
  float*  wtro    = halt + (size_t)BBATCH * CDIM;
  float*  wtrc    = wtro + (size_t)HDIM * CDIM;
  int*    rowlive = (int*)(wtrc + (size_t)577 * CDIM);
  int*    alive   = rowlive + BBATCH;

  k_init<<<145, 256, 0, stream>>>(wtro, W_out, wtrc, W_ctrl, rowlive, alive);

  for (int t = 0; t < TSPLIT; ++t) {
    const double* hR = (t & 1) ? h1 : h0;
    double*       hW = (t & 1) ? h0 : h1;
    k_phase1<<<dim3(64, 16), 256, 0, stream>>>(X, W_ih, W_hh, b_ih, b_hh,
                                               hR, hW, cst, ybar, rowlive, alive, t);
    k_phase2_512<<<BBATCH, 512, 0, stream>>>(hW, wtro, b_out, wtrc, b_ctrl, noise,
                                             epoch, ybar, preds, halt, ylast,
                                             rowlive, alive, t);
  }

  {
    void* args[] = {
      (void*)&X, (void*)&W_ih, (void*)&W_hh, (void*)&b_ih, (void*)&b_hh,
      (void*)&wtro, (void*)&b_out, (void*)&wtrc, (void*)&b_ctrl, (void*)&noise,
      (void*)&epoch, (void*)&h0, (void*)&h1, (void*)&cst, (void*)&ybar,
      (void*)&preds, (void*)&halt, (void*)&ylast, (void*)&rowlive, (void*)&alive
    };
    hipLaunchCooperativeKernel((const void*)k_tailloop, dim3(1024), dim3(256),
                               args, 0, stream);
  }

  k_final_out<<<64, 256, 0, stream>>>(preds, ylast, out);
  k_final_mean<<<1, 256, 0, stream>>>(halt, out);
}